// Round 1
// baseline (998.337 us; speedup 1.0000x reference)
//
#include <hip/hip_runtime.h>
#include <math.h>

namespace {
constexpr int B_N = 4;
constexpr int T_N = 128;
constexpr int P_N = 256;
constexpr int D_N = 512;
constexpr int S_N = 64;
constexpr int R_N = 8;
constexpr int KC  = 32;      // K chunk of D
constexpr int NTH = 256;

// LDS layout in floats
constexpr int XS_LD  = 34;                       // padded row stride
constexpr int XS_OFF = 0;                        // Xs[128][34]
constexpr int WS_OFF = XS_OFF + T_N * XS_LD;     // Ws[192][34]  (u rows 0-63, B 64-127, C 128-191)
constexpr int WD_OFF = WS_OFF + 192 * XS_LD;     // Wd[8][34]
constexpr int DTF_OFF = WD_OFF + 8 * XS_LD;      // dtf[128][8]; dt packed into slot [t][0] after reduce
constexpr int BUH_OFF = DTF_OFF + T_N * 8;       // BuH[128][64]: Bu -> H -> C*H (in place)
constexpr int ROS_LD  = 66;
constexpr int ROS_OFF = 0;                       // ros[128][66] overlays dead Xs/Ws after GEMM phase
constexpr int LDS_FLOATS = BUH_OFF + T_N * S_N;  // 20368 floats = 81472 B (2 blocks/CU)
}

__global__ __launch_bounds__(NTH, 2) void mamba_fused(
    const float* __restrict__ X, const float* __restrict__ H0,
    const float* __restrict__ a_hat,
    const float* __restrict__ U_w, const float* __restrict__ sB_w, const float* __restrict__ sB_b,
    const float* __restrict__ sC_w, const float* __restrict__ sC_b,
    const float* __restrict__ sD1_w, const float* __restrict__ sD1_b,
    const float* __restrict__ sD2_w, const float* __restrict__ sD2_b,
    const float* __restrict__ ro_w,
    float* __restrict__ Hseq, float* __restrict__ Y, float* __restrict__ HT)
{
    __shared__ float sm[LDS_FLOATS];
    const int tid = threadIdx.x;
    const int blk = blockIdx.x;
    const int b = blk >> 8;      // / P_N
    const int p = blk & 255;     // % P_N

    // projection-GEMM thread mapping: 32 row-groups x 8 s-groups
    const int tg    = tid >> 3;        // 0..31 -> rows tg*4 .. tg*4+3
    const int ng    = tid & 7;         // 0..7  -> s cols ng*8 .. ng*8+7
    const int sBase = ng * 8;
    const int rowdt = tid >> 1;        // 0..127 (dt-feat row)
    const int rbase = (tid & 1) * 4;   // dt-feat r offset (0 or 4)

    float au[4][8], ab_[4][8], ac[4][8], adt[4];
    #pragma unroll
    for (int i = 0; i < 4; ++i) {
        adt[i] = 0.0f;
        #pragma unroll
        for (int j = 0; j < 8; ++j) { au[i][j] = 0.0f; ab_[i][j] = 0.0f; ac[i][j] = 0.0f; }
    }

    const float* Xbp = X + ((size_t)b * T_N * P_N + p) * D_N;  // row t at + t*P_N*D_N

    // ---------- Phase 1: projections (u, B, C, dt_feat) over K = D ----------
    for (int kc0 = 0; kc0 < D_N; kc0 += KC) {
        __syncthreads();
        // stage X rows: 128 * 16 float2
        for (int fi = tid; fi < T_N * (KC / 2); fi += NTH) {
            int t = fi >> 4, k2 = fi & 15;
            *(float2*)&sm[XS_OFF + t * XS_LD + k2 * 2] =
                *(const float2*)(Xbp + (size_t)t * P_N * D_N + kc0 + k2 * 2);
        }
        // stage weights: 192 * 16 float2
        for (int fi = tid; fi < 192 * (KC / 2); fi += NTH) {
            int row = fi >> 4, k2 = fi & 15;
            const float* src = (row < 64) ? (U_w + row * D_N)
                              : (row < 128) ? (sB_w + (row - 64) * D_N)
                                            : (sC_w + (row - 128) * D_N);
            *(float2*)&sm[WS_OFF + row * XS_LD + k2 * 2] = *(const float2*)(src + kc0 + k2 * 2);
        }
        // stage dt weights: 8 * 16 float2
        if (tid < 128) {
            int row = tid >> 4, k2 = tid & 15;
            *(float2*)&sm[WD_OFF + row * XS_LD + k2 * 2] =
                *(const float2*)(sD1_w + row * D_N + kc0 + k2 * 2);
        }
        __syncthreads();

        #pragma unroll 4
        for (int k = 0; k < KC; ++k) {
            float xv[4];
            #pragma unroll
            for (int i = 0; i < 4; ++i) xv[i] = sm[XS_OFF + (tg * 4 + i) * XS_LD + k];
            float xd = sm[XS_OFF + rowdt * XS_LD + k];
            #pragma unroll
            for (int j = 0; j < 8; ++j) {
                float wu = sm[WS_OFF + (sBase + j) * XS_LD + k];
                float wb = sm[WS_OFF + (64 + sBase + j) * XS_LD + k];
                float wc = sm[WS_OFF + (128 + sBase + j) * XS_LD + k];
                #pragma unroll
                for (int i = 0; i < 4; ++i) {
                    au[i][j]  = fmaf(xv[i], wu, au[i][j]);
                    ab_[i][j] = fmaf(xv[i], wb, ab_[i][j]);
                    ac[i][j]  = fmaf(xv[i], wc, ac[i][j]);
                }
            }
            #pragma unroll
            for (int i = 0; i < 4; ++i)
                adt[i] = fmaf(xd, sm[WD_OFF + (rbase + i) * XS_LD + k], adt[i]);
        }
    }
    __syncthreads();

    // ---------- epilogue of phase 1: Bu = B*u to LDS, silu(dt_feat) to LDS, C += bias (regs) ----------
    #pragma unroll
    for (int i = 0; i < 4; ++i) {
        int row = tg * 4 + i;
        #pragma unroll
        for (int j = 0; j < 8; ++j) {
            int s = sBase + j;
            float bb = ab_[i][j] + sB_b[s];
            sm[BUH_OFF + row * S_N + s] = au[i][j] * bb;
            ac[i][j] += sC_b[s];
        }
    }
    #pragma unroll
    for (int i = 0; i < 4; ++i) {
        float z = adt[i] + sD1_b[rbase + i];
        float sg = 1.0f / (1.0f + expf(-z));      // silu
        sm[DTF_OFF + rowdt * 8 + rbase + i] = z * sg;
    }
    __syncthreads();

    // dt[t] = softplus(dtf . sD2_w + sD2_b), packed into dtf[t][0]
    if (tid < 128) {
        float z = sD2_b[0];
        #pragma unroll
        for (int r = 0; r < R_N; ++r) z = fmaf(sm[DTF_OFF + tid * 8 + r], sD2_w[r], z);
        float dtv = (z > 20.0f) ? z : log1pf(expf(z));
        sm[DTF_OFF + tid * 8] = dtv;
    }
    __syncthreads();

    // ---------- Phase 2: sequential scan over t (wave 0), ros chunk-0 prefetch (waves 1-3) ----------
    if (tid < 64) {
        const int s = tid;
        const float logA = -expf(a_hat[s]);
        const float h0 = H0[(b * P_N + p) * S_N + s];
        float Pcv = 1.0f, cv = 0.0f;
        float* HseqBase = Hseq + ((size_t)(b * T_N) * P_N + p) * S_N + s;
        for (int t = 0; t < T_N; ++t) {
            float dtv = sm[DTF_OFF + t * 8];
            float A = expf(dtv * logA);
            float bv = (1.0f - A) * sm[BUH_OFF + t * S_N + s];
            Pcv *= fmaxf(A, 1e-12f);
            cv += bv / fmaxf(Pcv, 1e-12f);
            float Hv = Pcv * (h0 + cv);
            HseqBase[(size_t)t * P_N * S_N] = Hv;
            sm[BUH_OFF + t * S_N + s] = Hv;     // in-place: Bu consumed at this t
            if (t == T_N - 1) HT[(b * P_N + p) * S_N + s] = Hv;
        }
    } else {
        for (int fi = tid - 64; fi < 128 * 32; fi += 192) {
            int dd = fi >> 5, s2 = fi & 31;
            *(float2*)&sm[ROS_OFF + dd * ROS_LD + s2 * 2] = *(const float2*)(ro_w + dd * S_N + s2 * 2);
        }
    }
    __syncthreads();

    // CH = C * H in place (each (t,s) owned by exactly one thread)
    #pragma unroll
    for (int i = 0; i < 4; ++i) {
        int row = tg * 4 + i;
        #pragma unroll
        for (int j = 0; j < 8; ++j) sm[BUH_OFF + row * S_N + sBase + j] *= ac[i][j];
    }
    __syncthreads();

    // ---------- Phase 3: Y = CH (128x64) x ro^T (64x512), in 4 d-chunks of 128 ----------
    const int dg  = tid & 15;   // d sub-block: cols dg*8..dg*8+7
    const int ttg = tid >> 4;   // t group: rows ttg*8..ttg*8+7
    for (int c = 0; c < 4; ++c) {
        float yacc[8][8];
        #pragma unroll
        for (int i = 0; i < 8; ++i)
            #pragma unroll
            for (int j = 0; j < 8; ++j) yacc[i][j] = 0.0f;

        for (int s = 0; s < S_N; ++s) {
            float ch[8], rv[8];
            #pragma unroll
            for (int i = 0; i < 8; ++i) ch[i] = sm[BUH_OFF + (ttg * 8 + i) * S_N + s];
            #pragma unroll
            for (int j = 0; j < 8; ++j) rv[j] = sm[ROS_OFF + (dg * 8 + j) * ROS_LD + s];
            #pragma unroll
            for (int i = 0; i < 8; ++i)
                #pragma unroll
                for (int j = 0; j < 8; ++j) yacc[i][j] = fmaf(ch[i], rv[j], yacc[i][j]);
        }
        #pragma unroll
        for (int i = 0; i < 8; ++i) {
            int t = ttg * 8 + i;
            float* yrow = Y + ((size_t)(b * T_N + t) * P_N + p) * D_N + c * 128 + dg * 8;
            *(float4*)yrow       = make_float4(yacc[i][0], yacc[i][1], yacc[i][2], yacc[i][3]);
            *(float4*)(yrow + 4) = make_float4(yacc[i][4], yacc[i][5], yacc[i][6], yacc[i][7]);
        }
        if (c < 3) {
            __syncthreads();
            for (int fi = tid; fi < 128 * 32; fi += NTH) {
                int dd = fi >> 5, s2 = fi & 31;
                *(float2*)&sm[ROS_OFF + dd * ROS_LD + s2 * 2] =
                    *(const float2*)(ro_w + ((c + 1) * 128 + dd) * S_N + s2 * 2);
            }
            __syncthreads();
        }
    }
}

extern "C" void kernel_launch(void* const* d_in, const int* in_sizes, int n_in,
                              void* d_out, int out_size, void* d_ws, size_t ws_size,
                              hipStream_t stream) {
    const float* X     = (const float*)d_in[0];
    const float* H0    = (const float*)d_in[1];
    const float* a_hat = (const float*)d_in[2];
    const float* U_w   = (const float*)d_in[3];
    const float* sB_w  = (const float*)d_in[4];
    const float* sB_b  = (const float*)d_in[5];
    const float* sC_w  = (const float*)d_in[6];
    const float* sC_b  = (const float*)d_in[7];
    const float* sD1_w = (const float*)d_in[8];
    const float* sD1_b = (const float*)d_in[9];
    const float* sD2_w = (const float*)d_in[10];
    const float* sD2_b = (const float*)d_in[11];
    const float* ro_w  = (const float*)d_in[12];

    float* out  = (float*)d_out;
    float* HseqP = out;
    float* YP    = out + (size_t)B_N * T_N * P_N * S_N;                         // 8388608
    float* HTP   = YP  + (size_t)B_N * T_N * P_N * D_N;                         // +67108864

    hipLaunchKernelGGL(mamba_fused, dim3(B_N * P_N), dim3(NTH), 0, stream,
                       X, H0, a_hat, U_w, sB_w, sB_b, sC_w, sC_b,
                       sD1_w, sD1_b, sD2_w, sD2_b, ro_w, HseqP, YP, HTP);
}

// Round 3
// 179.983 us; speedup vs baseline: 5.5468x; 5.5468x over previous
//
#include <hip/hip_runtime.h>
#include <math.h>

namespace {
constexpr int B_N = 4;
constexpr int T_N = 128;
constexpr int P_N = 256;
constexpr int D_N = 512;
constexpr int S_N = 64;
constexpr int NTH = 512;
constexpr int KC  = 64;

// LDS byte offsets. Liveness (all transitions barrier-protected):
//   phase1 k-loop : XS [0,16384) + WS [16384,43008)
//   epilogue+scan : UBUF f32 [0,32768) + BBUF bf16 [32768,49152) + CHB [49152,65536) + DT + LA
//   phase3        : ROS [0,32768) (UBUF dead) + CHB + outputs
constexpr int XS_OFF  = 0;
constexpr int WS_OFF  = 16384;
constexpr int UB_OFF  = 0;
constexpr int BB_OFF  = 32768;
constexpr int CH_OFF  = 49152;
constexpr int ROS_OFF = 0;
constexpr int DT_OFF  = 65536;
constexpr int LA_OFF  = 66048;
constexpr int LDS_BYTES = 66304;
}

typedef short bf16x8 __attribute__((ext_vector_type(8)));
typedef float f32x4  __attribute__((ext_vector_type(4)));

__device__ __forceinline__ unsigned short f2b(float f) {
    unsigned int x = __float_as_uint(f);
    return (unsigned short)((x + 0x7FFFu + ((x >> 16) & 1u)) >> 16);  // RNE
}
__device__ __forceinline__ float b2f(unsigned short h) {
    return __uint_as_float(((unsigned int)h) << 16);
}
// XOR-swizzled element index into a [rows][64] bf16 tile (16B-unit permute within 128B row)
__device__ __forceinline__ int swz(int row, int col) {
    return row * 64 + (col ^ ((row & 7) << 3));
}

// load 16 contiguous f32 from src, convert to bf16, store as two swizzled b128s
__device__ __forceinline__ void stage16(unsigned short* tile, int row, int col0,
                                        const float* __restrict__ src) {
    float4 v0 = *(const float4*)(src);
    float4 v1 = *(const float4*)(src + 4);
    float4 v2 = *(const float4*)(src + 8);
    float4 v3 = *(const float4*)(src + 12);
    bf16x8 h0, h1;
    h0[0] = (short)f2b(v0.x); h0[1] = (short)f2b(v0.y); h0[2] = (short)f2b(v0.z); h0[3] = (short)f2b(v0.w);
    h0[4] = (short)f2b(v1.x); h0[5] = (short)f2b(v1.y); h0[6] = (short)f2b(v1.z); h0[7] = (short)f2b(v1.w);
    h1[0] = (short)f2b(v2.x); h1[1] = (short)f2b(v2.y); h1[2] = (short)f2b(v2.z); h1[3] = (short)f2b(v2.w);
    h1[4] = (short)f2b(v3.x); h1[5] = (short)f2b(v3.y); h1[6] = (short)f2b(v3.z); h1[7] = (short)f2b(v3.w);
    *(bf16x8*)&tile[swz(row, col0)]     = h0;
    *(bf16x8*)&tile[swz(row, col0 + 8)] = h1;
}

__global__ __launch_bounds__(NTH, 4) void mamba_mfma(
    const float* __restrict__ X, const float* __restrict__ H0,
    const float* __restrict__ a_hat,
    const float* __restrict__ U_w, const float* __restrict__ sB_w, const float* __restrict__ sB_b,
    const float* __restrict__ sC_w, const float* __restrict__ sC_b,
    const float* __restrict__ sD1_w, const float* __restrict__ sD1_b,
    const float* __restrict__ sD2_w, const float* __restrict__ sD2_b,
    const float* __restrict__ ro_w,
    float* __restrict__ Hseq, float* __restrict__ Y, float* __restrict__ HT)
{
    __shared__ __align__(16) char smem[LDS_BYTES];
    unsigned short* XS  = (unsigned short*)(smem + XS_OFF);
    unsigned short* WS  = (unsigned short*)(smem + WS_OFF);
    float*          UBUF= (float*)(smem + UB_OFF);
    unsigned short* BBUF= (unsigned short*)(smem + BB_OFF);
    unsigned short* ROS = (unsigned short*)(smem + ROS_OFF);
    unsigned short* CHB = (unsigned short*)(smem + CH_OFF);
    float*          DTB = (float*)(smem + DT_OFF);
    float*          LA  = (float*)(smem + LA_OFF);

    const int tid  = threadIdx.x;
    const int lane = tid & 63;
    const int wid  = tid >> 6;
    const int wm   = wid >> 2;     // 0..1  (64-row stripe)
    const int wn   = wid & 3;      // 0..3
    const int l15  = lane & 15;
    const int lg   = lane >> 4;    // 0..3
    const int b    = blockIdx.x >> 8;
    const int p    = blockIdx.x & 255;

    if (tid < S_N) LA[tid] = -expf(a_hat[tid]);
    // zero WS rows 200..207 (dt B-frag garbage cols; never staged in k-loop)
    if (tid < 256) ((unsigned int*)(WS + 200 * 64))[tid] = 0;

    // ---------------- Phase 1: projection GEMM, M=128(t) N=192(+dt) K=512(d) ----------------
    f32x4 acc[4][3];
    f32x4 accdt[4];
    #pragma unroll
    for (int mf = 0; mf < 4; ++mf) {
        #pragma unroll
        for (int q = 0; q < 4; ++q) accdt[mf][q] = 0.0f;
        #pragma unroll
        for (int nf = 0; nf < 3; ++nf)
            #pragma unroll
            for (int q = 0; q < 4; ++q) acc[mf][nf][q] = 0.0f;
    }

    const int xr = tid >> 2;   // 0..127 (t row)
    const int xq = tid & 3;    // 0..3   (16-float quad)
    const float* xbase = X + (((size_t)b * T_N + xr) * P_N + p) * D_N + xq * 16;

    for (int kc0 = 0; kc0 < D_N; kc0 += KC) {
        stage16(XS, xr, xq * 16, xbase + kc0);
        for (int idx = tid; idx < 800; idx += NTH) {   // 200 rows x 4 quads
            int row = idx >> 2, kq = idx & 3;
            const float* wsrc;
            if (row < 64)       wsrc = U_w   + (size_t)row * D_N;
            else if (row < 128) wsrc = sB_w  + (size_t)(row - 64) * D_N;
            else if (row < 192) wsrc = sC_w  + (size_t)(row - 128) * D_N;
            else                wsrc = sD1_w + (size_t)(row - 192) * D_N;
            stage16(WS, row, kq * 16, wsrc + kc0 + kq * 16);
        }
        __syncthreads();
        #pragma unroll
        for (int kf = 0; kf < 2; ++kf) {
            const int kb = kf * 32 + lg * 8;   // consistent A/B k-permutation
            bf16x8 a[4];
            #pragma unroll
            for (int mf = 0; mf < 4; ++mf)
                a[mf] = *(const bf16x8*)&XS[swz(wm * 64 + mf * 16 + l15, kb)];
            #pragma unroll
            for (int nf = 0; nf < 3; ++nf) {
                bf16x8 bb = *(const bf16x8*)&WS[swz(wn * 48 + nf * 16 + l15, kb)];
                #pragma unroll
                for (int mf = 0; mf < 4; ++mf)
                    acc[mf][nf] = __builtin_amdgcn_mfma_f32_16x16x32_bf16(a[mf], bb, acc[mf][nf], 0, 0, 0);
            }
            if (wn == 0) {   // dt-feat extra N-frag (cols 0..7 valid, 8..15 zeros)
                bf16x8 bd = *(const bf16x8*)&WS[swz(192 + l15, kb)];
                #pragma unroll
                for (int mf = 0; mf < 4; ++mf)
                    accdt[mf] = __builtin_amdgcn_mfma_f32_16x16x32_bf16(a[mf], bd, accdt[mf], 0, 0, 0);
            }
        }
        __syncthreads();
    }

    // ---------------- Phase 1 epilogue: scatter u/B/C fragments, dt reduce ----------------
    // C/D frag layout (m89-verified): col = lane&15, row = (lane>>4)*4 + reg
    #pragma unroll
    for (int nf = 0; nf < 3; ++nf) {
        const int abscol = wn * 48 + nf * 16 + l15;
        const int kind = abscol >> 6;        // 0=u 1=B 2=C  (uniform per (wn,nf))
        const int s = abscol & 63;
        const float bias = (kind == 0) ? 0.0f : (kind == 1 ? sB_b[s] : sC_b[s]);
        #pragma unroll
        for (int mf = 0; mf < 4; ++mf) {
            #pragma unroll
            for (int q = 0; q < 4; ++q) {
                const int t = wm * 64 + mf * 16 + lg * 4 + q;
                const float v = acc[mf][nf][q] + bias;
                if (kind == 0)      UBUF[t * 64 + s] = v;          // u (f32)
                else if (kind == 1) BBUF[t * 64 + s] = f2b(v);     // B+bias (bf16)
                else                CHB[swz(t, s)]   = f2b(v);     // C+bias (bf16)
            }
        }
    }
    if (wn == 0) {
        const float w2 = (l15 < 8) ? sD2_w[l15] : 0.0f;
        const float b1 = (l15 < 8) ? sD1_b[l15] : 0.0f;
        const float b2 = sD2_b[0];
        #pragma unroll
        for (int mf = 0; mf < 4; ++mf) {
            #pragma unroll
            for (int q = 0; q < 4; ++q) {
                float z = accdt[mf][q] + b1;
                float w = (z / (1.0f + expf(-z))) * w2;   // silu * sD2_w
                w = (l15 < 8) ? w : 0.0f;
                w += __shfl_xor(w, 1);
                w += __shfl_xor(w, 2);
                w += __shfl_xor(w, 4);
                if (l15 == 0) {
                    float zz = w + b2;
                    DTB[wm * 64 + mf * 16 + lg * 4 + q] = (zz > 20.0f) ? zz : log1pf(expf(zz));
                }
            }
        }
    }
    __syncthreads();

    // ---------------- Phase 2: sequential scan (reference clamp semantics, fp32) ----------------
    if (tid < 64) {
        const int s = tid;
        const float la = LA[s];
        const float h0 = H0[((size_t)b * P_N + p) * S_N + s];
        float Pcv = 1.0f, cv = 0.0f, Hv = 0.0f;
        float* hout = Hseq + ((size_t)b * T_N * P_N + p) * S_N + s;
        for (int t = 0; t < T_N; ++t) {
            const float Av = expf(DTB[t] * la);
            const float bv = (1.0f - Av) * (b2f(BBUF[t * 64 + s]) * UBUF[t * 64 + s]);
            Pcv *= fmaxf(Av, 1e-12f);                 // Pc = cumprod(max(A,eps))
            cv += bv * (1.0f / fmaxf(Pcv, 1e-12f));   // c += b * invP (reference rounding order)
            Hv = Pcv * (h0 + cv);
            hout[(size_t)t * P_N * S_N] = Hv;
            const int e = swz(t, s);
            CHB[e] = f2b(b2f(CHB[e]) * Hv);           // CH = C * H (bf16)
        }
        HT[((size_t)b * P_N + p) * S_N + s] = Hv;
    }
    __syncthreads();

    // ---------------- Phase 3: Y = CH(128x64) x ro^T(64x512), two 256-wide passes ----------------
    for (int pp = 0; pp < 2; ++pp) {
        #pragma unroll
        for (int i = 0; i < 2; ++i) {                 // 256 rows x 4 quads = 1024 units
            const int idx = i * 512 + tid;
            const int row = idx >> 2, kq = idx & 3;
            stage16(ROS, row, kq * 16, ro_w + ((size_t)(pp * 256 + row)) * S_N + kq * 16);
        }
        __syncthreads();
        f32x4 yacc[4][4];
        #pragma unroll
        for (int mf = 0; mf < 4; ++mf)
            #pragma unroll
            for (int nf = 0; nf < 4; ++nf)
                #pragma unroll
                for (int q = 0; q < 4; ++q) yacc[mf][nf][q] = 0.0f;
        #pragma unroll
        for (int kf = 0; kf < 2; ++kf) {
            const int kb = kf * 32 + lg * 8;
            bf16x8 a[4];
            #pragma unroll
            for (int mf = 0; mf < 4; ++mf)
                a[mf] = *(const bf16x8*)&CHB[swz(wm * 64 + mf * 16 + l15, kb)];
            #pragma unroll
            for (int nf = 0; nf < 4; ++nf) {
                bf16x8 bb = *(const bf16x8*)&ROS[swz(wn * 64 + nf * 16 + l15, kb)];
                #pragma unroll
                for (int mf = 0; mf < 4; ++mf)
                    yacc[mf][nf] = __builtin_amdgcn_mfma_f32_16x16x32_bf16(a[mf], bb, yacc[mf][nf], 0, 0, 0);
            }
        }
        #pragma unroll
        for (int mf = 0; mf < 4; ++mf) {
            const int t0 = wm * 64 + mf * 16 + lg * 4;
            float* ybase = Y + (((size_t)b * T_N + t0) * P_N + p) * D_N + pp * 256 + wn * 64 + l15;
            #pragma unroll
            for (int nf = 0; nf < 4; ++nf) {
                #pragma unroll
                for (int q = 0; q < 4; ++q)
                    ybase[(size_t)q * P_N * D_N + nf * 16] = yacc[mf][nf][q];
            }
        }
        if (pp == 0) __syncthreads();
    }
}

extern "C" void kernel_launch(void* const* d_in, const int* in_sizes, int n_in,
                              void* d_out, int out_size, void* d_ws, size_t ws_size,
                              hipStream_t stream) {
    const float* X     = (const float*)d_in[0];
    const float* H0    = (const float*)d_in[1];
    const float* a_hat = (const float*)d_in[2];
    const float* U_w   = (const float*)d_in[3];
    const float* sB_w  = (const float*)d_in[4];
    const float* sB_b  = (const float*)d_in[5];
    const float* sC_w  = (const float*)d_in[6];
    const float* sC_b  = (const float*)d_in[7];
    const float* sD1_w = (const float*)d_in[8];
    const float* sD1_b = (const float*)d_in[9];
    const float* sD2_w = (const float*)d_in[10];
    const float* sD2_b = (const float*)d_in[11];
    const float* ro_w  = (const float*)d_in[12];

    float* out   = (float*)d_out;
    float* HseqP = out;
    float* YP    = out + (size_t)B_N * T_N * P_N * S_N;
    float* HTP   = YP  + (size_t)B_N * T_N * P_N * D_N;

    hipLaunchKernelGGL(mamba_mfma, dim3(B_N * P_N), dim3(NTH), 0, stream,
                       X, H0, a_hat, U_w, sB_w, sB_b, sC_w, sC_b,
                       sD1_w, sD1_b, sD2_w, sD2_b, ro_w, HseqP, YP, HTP);
}